// Round 7
// baseline (617.363 us; speedup 1.0000x reference)
//
#include <hip/hip_runtime.h>

// Problem constants (match reference)
constexpr int N     = 262144;  // rows
constexpr int C     = 1000;    // classes
constexpr int D     = 256;     // feature dim
constexpr int CPAD  = 1024;    // padded class count for hist
constexpr int NB    = 64;      // hist blocks
constexpr int SLICES = 16;     // D is split into 16 slices of 16 dims
constexpr int SDIM   = 16;     // dims per slice
constexpr int NCHUNK = 32;     // row chunks per slice
constexpr int ROWS_PER_CHUNK = N / NCHUNK;       // 8192
constexpr int TBL = C * SDIM;                    // 16000 floats = 62.5 KB LDS
constexpr float ALPHA = 0.5f;

typedef float vfloat4 __attribute__((ext_vector_type(4)));

// ---------------- workspace layout (d_ws) ----------------
// int   counts [CPAD]                     4 KB (memsetAsync to 0, hist atomics)
// float partials[SLICES*NCHUNK][TBL]     32 MB (fully written by partial kernel)

// 64 blocks: LDS histogram of labels, then 1024 global atomic adds per block
// into counts (64 adds per class total -- negligible contention).
__global__ __launch_bounds__(256) void hist_kernel(
        const int* __restrict__ labels, int* __restrict__ counts) {
    __shared__ int h[CPAD];
    int t = threadIdx.x;
    for (int i = t; i < CPAD; i += 256) h[i] = 0;
    __syncthreads();
    int base = blockIdx.x * (N / NB);
    for (int i = t; i < N / NB; i += 256)
        atomicAdd(&h[labels[base + i]], 1);
    __syncthreads();
    for (int i = t; i < CPAD; i += 256)
        if (h[i]) atomicAdd(&counts[i], h[i]);
}

// 512 blocks = 16 slices x 32 chunks; 2 blocks/CU (62.5 KB LDS each).
// Block (s,chunk) streams rows [chunk*8192,(chunk+1)*8192) SEQUENTIALLY,
// reading only dims [s*16, s*16+16) of each row (64 B granule), and
// accumulates into an LDS class table via native ds_add_f32.
// Swizzle ((d + c) & 15) spreads label-parity bank collisions.
// Thread map: q = t&3 covers 4 dims (one float4), rg = t>>2 is row lane.
__global__ __launch_bounds__(256) void partial_kernel(
        const vfloat4* __restrict__ feat4,
        const int* __restrict__ labels,
        float* __restrict__ partials) {
    __shared__ float tbl[TBL];
    int t = threadIdx.x;
    for (int i = t; i < TBL; i += 256) tbl[i] = 0.f;
    __syncthreads();

    int s     = blockIdx.x >> 5;          // slice 0..15
    int chunk = blockIdx.x & 31;          // chunk 0..31
    int q     = t & 3;                    // float4 within slice
    int rg    = t >> 2;                   // 0..63 row lane
    int base  = chunk * ROWS_PER_CHUNK;

    // 8192 rows, 64 in flight per pass, 128 passes, unrolled 8-deep.
    #pragma unroll 1
    for (int outer = 0; outer < ROWS_PER_CHUNK / 64; outer += 8) {
        int lab[8];
        vfloat4 v[8];
        #pragma unroll
        for (int j = 0; j < 8; ++j) {
            int row = base + (outer + j) * 64 + rg;
            lab[j] = labels[row];
            v[j]   = feat4[(long)row * 64 + s * 4 + q];
        }
        #pragma unroll
        for (int j = 0; j < 8; ++j) {
            int cl = lab[j];
            int b0 = q * 4 + cl;          // swizzle base
            atomicAdd(&tbl[cl * SDIM + ((b0 + 0) & 15)], v[j].x);
            atomicAdd(&tbl[cl * SDIM + ((b0 + 1) & 15)], v[j].y);
            atomicAdd(&tbl[cl * SDIM + ((b0 + 2) & 15)], v[j].z);
            atomicAdd(&tbl[cl * SDIM + ((b0 + 3) & 15)], v[j].w);
        }
    }
    __syncthreads();

    // Flush: unswizzle from LDS, coalesced global write of this block's table.
    float* dst = partials + (long)blockIdx.x * TBL;
    for (int i = t; i < TBL; i += 256) {
        int cl = i >> 4, d = i & 15;
        dst[i] = tbl[cl * SDIM + ((d + cl) & 15)];
    }
}

// EMA epilogue: one thread per output float4. Sums this element's 32 chunk
// partials (L3-resident), then o = (1-A)*cen + A*sum/cnt.
__global__ __launch_bounds__(256) void ema_kernel(
        const float4* __restrict__ cen4,
        const float* __restrict__ partials,
        const int* __restrict__ counts,
        float4* __restrict__ out4) {
    int idx = blockIdx.x * 256 + threadIdx.x;   // 0 .. C*64-1
    if (idx >= C * 64) return;
    int c   = idx >> 6;
    int d4  = idx & 63;                         // float4 index within row
    int s   = d4 >> 2;                          // slice
    int dis = (d4 & 3) * 4;                     // dim within slice
    int cnt = counts[c];
    float4 cen = cen4[idx];
    float4 o = cen;
    if (cnt > 0) {
        float sx = 0.f, sy = 0.f, sz = 0.f, sw = 0.f;
        const float* p = partials + (long)s * NCHUNK * TBL + c * SDIM + dis;
        #pragma unroll 8
        for (int ch = 0; ch < NCHUNK; ++ch) {
            const float* pp = p + (long)ch * TBL;
            sx += pp[0]; sy += pp[1]; sz += pp[2]; sw += pp[3];
        }
        float sc = ALPHA / (float)cnt;
        o.x = (1.0f - ALPHA) * cen.x + sx * sc;
        o.y = (1.0f - ALPHA) * cen.y + sy * sc;
        o.z = (1.0f - ALPHA) * cen.z + sz * sc;
        o.w = (1.0f - ALPHA) * cen.w + sw * sc;
    }
    out4[idx] = o;
}

extern "C" void kernel_launch(void* const* d_in, const int* in_sizes, int n_in,
                              void* d_out, int out_size, void* d_ws, size_t ws_size,
                              hipStream_t stream) {
    const vfloat4* feat4  = (const vfloat4*)d_in[0];
    const int*     labels = (const int*)d_in[1];
    const float4*  cen4   = (const float4*)d_in[2];
    float4*        out4   = (float4*)d_out;

    int*   counts   = (int*)d_ws;
    float* partials = (float*)(counts + CPAD);   // 512 * 16000 floats = 32 MB

    hipMemsetAsync(counts, 0, CPAD * sizeof(int), stream);
    hist_kernel<<<NB, 256, 0, stream>>>(labels, counts);
    partial_kernel<<<SLICES * NCHUNK, 256, 0, stream>>>(feat4, labels, partials);
    ema_kernel<<<(C * 64 + 255) / 256, 256, 0, stream>>>(cen4, partials, counts, out4);
}